// Round 2
// baseline (125.799 us; speedup 1.0000x reference)
//
#include <hip/hip_runtime.h>
#include <hip/hip_bf16.h>
#include <stdint.h>

#define M_TOTAL 32768
#define K_DIM   1024
#define N_DIM   1024

#define BM 128
#define BN 128
#define BK 64
#define A_TILE_B (BM * BK * 2)   // 16384 bytes
#define B_TILE_B (BN * BK * 2)   // 16384 bytes

typedef __attribute__((ext_vector_type(8))) short  short8;
typedef __attribute__((ext_vector_type(4))) float  f32x4;

__device__ __forceinline__ ushort f2bf(float f) {
  union { float f; uint32_t u; } v; v.f = f;
  uint32_t r = v.u + 0x7FFFu + ((v.u >> 16) & 1u);   // RNE, inputs are finite
  return (ushort)(r >> 16);
}

// ---------------- kernel 1: materialize Toeplitz matrix as bf16 -------------
__global__ __launch_bounds__(256) void build_T_kernel(
    const float* __restrict__ fr, const float* __restrict__ fc,
    ushort* __restrict__ T) {
  int idx = blockIdx.x * 256 + threadIdx.x;   // 131072 threads, 8 elems each
  int o  = idx >> 7;
  int i0 = (idx & 127) << 3;
  short8 v;
#pragma unroll
  for (int j = 0; j < 8; ++j) {
    int d = o - (i0 + j);
    float f = (d >= 0) ? fc[d] : fr[-d];
    v[j] = (short)f2bf(f);
  }
  *reinterpret_cast<short8*>(T + (size_t)idx * 8) = v;
}

// ---------------- kernel 2: bf16 MFMA GEMM ---------------------------------
__global__ __launch_bounds__(256, 2) void toeplitz_gemm(
    const float* __restrict__ X, const ushort* __restrict__ T,
    const float* __restrict__ bias, float* __restrict__ Out) {
  __shared__ alignas(16) char smem[2 * A_TILE_B + 2 * B_TILE_B];  // 64 KiB

  const int tid  = threadIdx.x;
  const int lane = tid & 63;
  const int wv   = tid >> 6;
  const int wr   = wv >> 1, wc = wv & 1;       // 2x2 wave grid, 64x64 each
  const int cc   = lane & 15, kg = lane >> 4;

  // XCD-bijective swizzle: 2048 blocks = 8 * 256
  int bid = blockIdx.x;
  int wg  = (bid & 7) * 256 + (bid >> 3);
  const int m0 = (wg >> 3) * BM;
  const int n0 = (wg & 7) * BN;

  // ---- A staging constants (reg-staged, fp32 -> bf16, swizzled ds_write)
  const int arow = tid >> 4;                    // + 16*i
  const int akq  = tid & 15;                    // float4 slot in row
  const float* xptr = X + (size_t)(m0 + arow) * K_DIM + akq * 4;
  const int aWoffBase = arow * 128 + ((akq * 8) ^ ((arow & 7) << 4)); // + i*2048

  // ---- B staging constants (global_load_lds, pre-swizzled global source)
  const int bnl = tid >> 3;                     // + g*32
  const int bkb = ((tid & 7) * 16) ^ (((tid >> 3) & 7) << 4);
  const ushort* tptr = T + (size_t)(n0 + bnl) * K_DIM + (bkb >> 1);
  const int bLdsBase = 2 * A_TILE_B + tid * 16; // + g*4096 + sel*B_TILE_B

  f32x4  areg[8];
  f32x4  acc[4][4] = {};

#define ISSUE_A(t)                                                          \
  { _Pragma("unroll")                                                       \
    for (int i = 0; i < 8; ++i)                                             \
      areg[i] = *reinterpret_cast<const f32x4*>(                            \
          xptr + (size_t)i * 16 * K_DIM + (size_t)(t) * BK); }

#define ISSUE_B(t, sel)                                                     \
  { _Pragma("unroll")                                                       \
    for (int g = 0; g < 4; ++g) {                                           \
      const ushort* src = tptr + (size_t)g * 32 * K_DIM + (size_t)(t) * BK; \
      char* dst = smem + bLdsBase + (sel) * B_TILE_B + g * 4096;            \
      __builtin_amdgcn_global_load_lds(                                     \
          (const __attribute__((address_space(1))) void*)src,               \
          (__attribute__((address_space(3))) void*)dst, 16, 0, 0);          \
    } }

#define WRITE_A(sel)                                                        \
  { _Pragma("unroll")                                                       \
    for (int i = 0; i < 8; ++i) {                                           \
      uint32_t lo = (uint32_t)f2bf(areg[i].x) |                             \
                    ((uint32_t)f2bf(areg[i].y) << 16);                      \
      uint32_t hi = (uint32_t)f2bf(areg[i].z) |                             \
                    ((uint32_t)f2bf(areg[i].w) << 16);                      \
      uint2 p; p.x = lo; p.y = hi;                                          \
      *reinterpret_cast<uint2*>(smem + (sel) * A_TILE_B + aWoffBase +       \
                                i * 2048) = p;                              \
    } }

#define COMPUTE(sel)                                                        \
  { const char* ab = smem + (sel) * A_TILE_B;                               \
    const char* bb = smem + 2 * A_TILE_B + (sel) * B_TILE_B;                \
    _Pragma("unroll")                                                       \
    for (int kk = 0; kk < 2; ++kk) {                                        \
      short8 af[4], bfr[4];                                                 \
      const int colb = (kk * 64 + kg * 16) ^ ((cc & 7) << 4);               \
      _Pragma("unroll")                                                     \
      for (int mf = 0; mf < 4; ++mf)                                        \
        af[mf] = *reinterpret_cast<const short8*>(                          \
            ab + (wr * 64 + mf * 16 + cc) * 128 + colb);                    \
      _Pragma("unroll")                                                     \
      for (int nf = 0; nf < 4; ++nf)                                        \
        bfr[nf] = *reinterpret_cast<const short8*>(                         \
            bb + (wc * 64 + nf * 16 + cc) * 128 + colb);                    \
      _Pragma("unroll")                                                     \
      for (int mf = 0; mf < 4; ++mf)                                        \
        _Pragma("unroll")                                                   \
        for (int nf = 0; nf < 4; ++nf)                                      \
          acc[mf][nf] = __builtin_amdgcn_mfma_f32_16x16x32_bf16(            \
              af[mf], bfr[nf], acc[mf][nf], 0, 0, 0);                       \
    } }

  // prologue: stage K-step 0 into buffer 0
  ISSUE_A(0);
  ISSUE_B(0, 0);
  WRITE_A(0);            // compiler inserts vmcnt wait for areg
  __syncthreads();       // drains vmcnt (B lds) + lgkm (A writes)

#pragma unroll 1
  for (int t = 0; t < 16; t += 2) {
    ISSUE_A(t + 1); ISSUE_B(t + 1, 1);
    COMPUTE(0);
    WRITE_A(1);
    __syncthreads();
    if (t + 2 < 16) { ISSUE_A(t + 2); ISSUE_B(t + 2, 0); }
    COMPUTE(1);
    if (t + 2 < 16) { WRITE_A(0); __syncthreads(); }
  }

  // epilogue: bias + fp32 store
#pragma unroll
  for (int nf = 0; nf < 4; ++nf) {
    const int col = n0 + wc * 64 + nf * 16 + cc;
    const float bv = bias[col];
#pragma unroll
    for (int mf = 0; mf < 4; ++mf) {
      const int row0 = m0 + wr * 64 + mf * 16 + kg * 4;
      float* op = Out + (size_t)row0 * N_DIM + col;
#pragma unroll
      for (int j = 0; j < 4; ++j)
        op[(size_t)j * N_DIM] = acc[mf][nf][j] + bv;
    }
  }
#undef ISSUE_A
#undef ISSUE_B
#undef WRITE_A
#undef COMPUTE
}

// ---------------- fallback (ws too small): naive fp32 ----------------------
__global__ __launch_bounds__(256) void toeplitz_naive(
    const float* __restrict__ x, const float* __restrict__ fr,
    const float* __restrict__ fc, const float* __restrict__ bias,
    float* __restrict__ out) {
  __shared__ float sx[1024], sfr[1024], sfc[1024];
  const int m = blockIdx.x;
  for (int i = threadIdx.x; i < 1024; i += 256) {
    sx[i]  = x[(size_t)m * 1024 + i];
    sfr[i] = fr[i];
    sfc[i] = fc[i];
  }
  __syncthreads();
  for (int q = 0; q < 4; ++q) {
    const int o = threadIdx.x + q * 256;
    float acc = bias[o];
    for (int i = 0; i <= o; ++i)       acc += sx[i] * sfc[o - i];
    for (int i = o + 1; i < 1024; ++i) acc += sx[i] * sfr[i - o];
    out[(size_t)m * 1024 + o] = acc;
  }
}

extern "C" void kernel_launch(void* const* d_in, const int* in_sizes, int n_in,
                              void* d_out, int out_size, void* d_ws, size_t ws_size,
                              hipStream_t stream) {
  const float* x    = (const float*)d_in[0];
  const float* fr   = (const float*)d_in[1];
  const float* fc   = (const float*)d_in[2];
  const float* bias = (const float*)d_in[3];
  float* out = (float*)d_out;

  if (ws_size >= (size_t)2 * 1024 * 1024) {
    ushort* T = (ushort*)d_ws;
    build_T_kernel<<<dim3(512), dim3(256), 0, stream>>>(fr, fc, T);
    toeplitz_gemm<<<dim3(2048), dim3(256), 0, stream>>>(x, T, bias, out);
  } else {
    toeplitz_naive<<<dim3(32768), dim3(256), 0, stream>>>(x, fr, fc, bias, out);
  }
}

// Round 3
// 107.345 us; speedup vs baseline: 1.1719x; 1.1719x over previous
//
#include <hip/hip_runtime.h>
#include <hip/hip_bf16.h>
#include <stdint.h>

#define K_DIM 1024
#define N_DIM 1024
#define BM 256
#define BN 256
#define BK 64
#define NKSTEP 16

typedef __attribute__((ext_vector_type(8))) short  short8;
typedef __attribute__((ext_vector_type(4))) float  f32x4;
typedef __attribute__((ext_vector_type(4))) unsigned int u32x4;

__device__ __forceinline__ ushort f2bf(float f) {
  union { float f; uint32_t u; } v; v.f = f;
  uint32_t r = v.u + 0x7FFFu + ((v.u >> 16) & 1u);
  return (ushort)(r >> 16);
}
__device__ __forceinline__ uint32_t f2bf2(float a, float b) {
  union { float f; uint32_t u; } x, y; x.f = a; y.f = b;
  uint32_t lo = x.u + 0x7FFFu + ((x.u >> 16) & 1u);
  uint32_t hi = y.u + 0x7FFFu + ((y.u >> 16) & 1u);
  return (lo >> 16) | (hi & 0xFFFF0000u);
}

// ---------------- kernel 1: materialize Toeplitz matrix as bf16 -------------
__global__ __launch_bounds__(256) void build_T_kernel(
    const float* __restrict__ fr, const float* __restrict__ fc,
    ushort* __restrict__ T) {
  int idx = blockIdx.x * 256 + threadIdx.x;
  int o  = idx >> 7;
  int i0 = (idx & 127) << 3;
  short8 v;
#pragma unroll
  for (int j = 0; j < 8; ++j) {
    int d = o - (i0 + j);
    float f = (d >= 0) ? fc[d] : fr[-d];
    v[j] = (short)f2bf(f);
  }
  *reinterpret_cast<short8*>(T + (size_t)idx * 8) = v;
}

// ---------------- kernel 2: 256x256 bf16 MFMA GEMM, 1-barrier/K-step --------
__global__ __launch_bounds__(512, 2) void toeplitz_gemm(
    const float* __restrict__ X, const ushort* __restrict__ T,
    const float* __restrict__ bias, float* __restrict__ Out) {
  // LDS: A dbuf [2][32KB] @0, B dbuf [2][32KB] @64KB  => 128 KiB
  __shared__ alignas(16) char smem[131072];

  const int tid  = threadIdx.x;
  const int lane = tid & 63;
  const int wv   = tid >> 6;
  const int wr   = wv >> 2;          // 0..1 (m)
  const int wn   = wv & 3;           // 0..3 (n)
  const int cc   = lane & 15, kg = lane >> 4;

  // XCD swizzle: 512 blocks = 8 XCD x 64; consecutive swz share m-panel.
  const int swz = (blockIdx.x & 7) * 64 + (blockIdx.x >> 3);
  const int m0 = (swz >> 2) * BM;
  const int n0 = (swz & 3) * BN;

  // ---- B staging (global_load_lds, pre-swizzled source) ----
  const int brow = tid >> 3;                         // + g*64
  const int bcb  = (tid & 7) * 16;
  const ushort* tptr = T + (size_t)(n0 + brow) * K_DIM
                         + ((bcb ^ ((brow & 7) << 4)) >> 1);
  const int bLds = 65536 + tid * 16;                 // + sel*32768 + g*8192

  // ---- A staging (reg-stage fp32 -> bf16, swizzled ds_write_b128) ----
  const float* xptr = X + (size_t)(m0 + (tid >> 3)) * K_DIM + (tid & 7) * 8;
  const int aW = (tid >> 3) * 128
               + ((16 * (tid & 7)) ^ (((tid >> 3) & 7) << 4)); // +sel*32768+i*8192

  // ---- fragment read constants ----
  const int aXor = (cc & 7) << 4;

  f32x4  areg[8];
  short8 bfr[4][2];
  f32x4  acc[8][4] = {};

#define ISSUE_A(t)                                                          \
  { _Pragma("unroll")                                                       \
    for (int i = 0; i < 4; ++i)                                             \
      _Pragma("unroll")                                                     \
      for (int j = 0; j < 2; ++j)                                           \
        areg[i * 2 + j] = *reinterpret_cast<const f32x4*>(                  \
            xptr + (size_t)i * 64 * K_DIM + (t) * BK + j * 4); }

#define ISSUE_B(t, sel)                                                     \
  { _Pragma("unroll")                                                       \
    for (int g = 0; g < 4; ++g) {                                           \
      const ushort* src = tptr + (size_t)g * 64 * K_DIM + (t) * BK;         \
      char* dst = smem + bLds + (sel) * 32768 + g * 8192;                   \
      __builtin_amdgcn_global_load_lds(                                     \
          (const __attribute__((address_space(1))) void*)src,               \
          (__attribute__((address_space(3))) void*)dst, 16, 0, 0);          \
    } }

#define WRITE_A(sel)                                                        \
  { _Pragma("unroll")                                                       \
    for (int i = 0; i < 4; ++i) {                                           \
      u32x4 p;                                                              \
      p.x = f2bf2(areg[2*i].x, areg[2*i].y);                                \
      p.y = f2bf2(areg[2*i].z, areg[2*i].w);                                \
      p.z = f2bf2(areg[2*i+1].x, areg[2*i+1].y);                            \
      p.w = f2bf2(areg[2*i+1].z, areg[2*i+1].w);                            \
      *reinterpret_cast<u32x4*>(smem + (sel) * 32768 + aW + i * 8192) = p;  \
    } }

#define READ_B(sel)                                                         \
  { _Pragma("unroll")                                                       \
    for (int nf = 0; nf < 4; ++nf)                                          \
      _Pragma("unroll")                                                     \
      for (int kk = 0; kk < 2; ++kk)                                        \
        bfr[nf][kk] = *reinterpret_cast<const short8*>(                     \
            smem + 65536 + (sel) * 32768 +                                  \
            (wn * 64 + nf * 16 + cc) * 128 +                                \
            ((kk * 64 + kg * 16) ^ aXor)); }

#define PHASE(sel, mf0)                                                     \
  { short8 afr[2][2];                                                       \
    _Pragma("unroll")                                                       \
    for (int q = 0; q < 2; ++q)                                             \
      _Pragma("unroll")                                                     \
      for (int kk = 0; kk < 2; ++kk)                                        \
        afr[q][kk] = *reinterpret_cast<const short8*>(                      \
            smem + (sel) * 32768 +                                          \
            (wr * 128 + (mf0 + q) * 16 + cc) * 128 +                        \
            ((kk * 64 + kg * 16) ^ aXor));                                  \
    __builtin_amdgcn_s_setprio(1);                                          \
    _Pragma("unroll")                                                       \
    for (int q = 0; q < 2; ++q)                                             \
      _Pragma("unroll")                                                     \
      for (int nf = 0; nf < 4; ++nf)                                        \
        _Pragma("unroll")                                                   \
        for (int kk = 0; kk < 2; ++kk)                                      \
          acc[mf0 + q][nf] = __builtin_amdgcn_mfma_f32_16x16x32_bf16(       \
              afr[q][kk], bfr[nf][kk], acc[mf0 + q][nf], 0, 0, 0);          \
    __builtin_amdgcn_s_setprio(0); }

  // prologue: stage K-step 0 into buffer 0
  ISSUE_A(0);
  ISSUE_B(0, 0);
  WRITE_A(0);            // compiler inserts vmcnt wait for areg
  __syncthreads();       // drains vmcnt (B DMA) + lgkm (A writes)

#pragma unroll 1
  for (int t = 0; t < NKSTEP; ++t) {
    const int cur = t & 1;
    const int nxt = cur ^ 1;
    if (t < NKSTEP - 1) { ISSUE_A(t + 1); ISSUE_B(t + 1, nxt); }
    READ_B(cur);
    PHASE(cur, 0);
    PHASE(cur, 2);
    PHASE(cur, 4);
    if (t < NKSTEP - 1) WRITE_A(nxt);   // areg vmcnt-waited here, late write
    PHASE(cur, 6);
    __syncthreads();                    // one barrier per K-step
  }

  // epilogue: bias + fp32 store
#pragma unroll
  for (int nf = 0; nf < 4; ++nf) {
    const int col = n0 + wn * 64 + nf * 16 + cc;
    const float bv = bias[col];
#pragma unroll
    for (int mf = 0; mf < 8; ++mf) {
      const int row0 = m0 + wr * 128 + mf * 16 + kg * 4;
      float* op = Out + (size_t)row0 * N_DIM + col;
#pragma unroll
      for (int j = 0; j < 4; ++j)
        op[(size_t)j * N_DIM] = acc[mf][nf][j] + bv;
    }
  }
#undef ISSUE_A
#undef ISSUE_B
#undef WRITE_A
#undef READ_B
#undef PHASE
}

// ---------------- fallback (ws too small): naive fp32 ----------------------
__global__ __launch_bounds__(256) void toeplitz_naive(
    const float* __restrict__ x, const float* __restrict__ fr,
    const float* __restrict__ fc, const float* __restrict__ bias,
    float* __restrict__ out) {
  __shared__ float sx[1024], sfr[1024], sfc[1024];
  const int m = blockIdx.x;
  for (int i = threadIdx.x; i < 1024; i += 256) {
    sx[i]  = x[(size_t)m * 1024 + i];
    sfr[i] = fr[i];
    sfc[i] = fc[i];
  }
  __syncthreads();
  for (int q = 0; q < 4; ++q) {
    const int o = threadIdx.x + q * 256;
    float acc = bias[o];
    for (int i = 0; i <= o; ++i)       acc += sx[i] * sfc[o - i];
    for (int i = o + 1; i < 1024; ++i) acc += sx[i] * sfr[i - o];
    out[(size_t)m * 1024 + o] = acc;
  }
}

extern "C" void kernel_launch(void* const* d_in, const int* in_sizes, int n_in,
                              void* d_out, int out_size, void* d_ws, size_t ws_size,
                              hipStream_t stream) {
  const float* x    = (const float*)d_in[0];
  const float* fr   = (const float*)d_in[1];
  const float* fc   = (const float*)d_in[2];
  const float* bias = (const float*)d_in[3];
  float* out = (float*)d_out;

  if (ws_size >= (size_t)2 * 1024 * 1024) {
    ushort* T = (ushort*)d_ws;
    build_T_kernel<<<dim3(512), dim3(256), 0, stream>>>(fr, fc, T);
    toeplitz_gemm<<<dim3(512), dim3(512), 0, stream>>>(x, T, bias, out);
  } else {
    toeplitz_naive<<<dim3(32768), dim3(256), 0, stream>>>(x, fr, fc, bias, out);
  }
}